// Round 7
// baseline (333.282 us; speedup 1.0000x reference)
//
#include <hip/hip_runtime.h>
#include <hip/hip_cooperative_groups.h>
#include <cstddef>

namespace cg = cooperative_groups;

// ----------------------------------------------------------------------------
// AttentionFusion round 6: cooperative mega-kernel with occupancy-sized grid +
// checked launch + multi-kernel fallback (same phase bodies either way).
// Phases: P1 sx/pyt GEMMs, P2 scores+softmax, P3 ctx, P4 FFN1(split-A),
// P5 FFN2, P6 LN stats, P7 LN apply + time-mean.
// ----------------------------------------------------------------------------

#define D_  768
#define NH_ 4
#define B_  4
#define T1_ 128
#define T2_ 128
#define M_  (B_*T1_)
#define LN_EPS_ 1e-5f

typedef unsigned short u16;
typedef unsigned int u32;
typedef _Float16 f16;
typedef _Float16 f16x2 __attribute__((ext_vector_type(2)));
typedef __bf16 bf16x8 __attribute__((ext_vector_type(8)));
typedef float f32x4 __attribute__((ext_vector_type(4)));

__device__ __forceinline__ u16 f16bits(f16 h) {
    return __builtin_bit_cast(unsigned short, h);
}
__device__ __forceinline__ f16x2 bcast2(u32 u) {
    return __builtin_bit_cast(f16x2, u);
}
__device__ __forceinline__ u32 splat2(u16 h) { return (u32)h * 0x10001u; }
__device__ __forceinline__ u32 pack_trunc(float lo, float hi) {
    u32 a = __builtin_bit_cast(u32, lo), b = __builtin_bit_cast(u32, hi);
    return (b & 0xFFFF0000u) | (a >> 16);
}

struct Params {
    const float *speech, *phon, *W1, *b1, *w2, *Wf1, *bf1, *Wf2, *bf2, *g, *lb;
    float* out;
    u16 *sxf, *pyt;
    float *probs, *ctx, *hbuf, *outpre, *rs, *prS;
};

#define SMEM_BYTES 28672

// ---------------- bf16 MFMA GEMM tile: C[64,64] = A[M,K]f32 @ B[K,N]f32 -----
// MODE: 0 = f32 rows, 2 = f16 rows, 3 = f16 transposed (pyt[b][h][s]).
template<int MODE, bool RELU, bool SPLIT>
__device__ __forceinline__ void gemm_tile(
    const float* __restrict__ A1, const float* __restrict__ A2, int lda,
    const float* __restrict__ B, int ldb,
    const float* __restrict__ bias, void* __restrict__ C, int ldc,
    int K, int m0, int n0, char* smem, int tid)
{
    u16 (*As)[40] = reinterpret_cast<u16(*)[40]>(smem);          //  5120 B
    u16 (*Bs)[40] = reinterpret_cast<u16(*)[40]>(smem + 5120);   //  5120 B
    u16 (*Ts)[68] = reinterpret_cast<u16(*)[68]>(smem + 10240);  //  8704 B (MODE 3)

    const int row = tid >> 2;
    const int kq  = (tid & 3) << 3;
    const int kp  = tid >> 4;
    const int nq  = (tid & 15) << 2;
    const int lane = tid & 63, w = tid >> 6;
    const int wr = (w >> 1) << 5, wc = (w & 1) << 5;
    const int l16 = lane & 15, lk8 = (lane >> 4) << 3, r4 = (lane >> 4) << 2;

    f32x4 acc00 = {0.f,0.f,0.f,0.f}, acc01 = {0.f,0.f,0.f,0.f};
    f32x4 acc10 = {0.f,0.f,0.f,0.f}, acc11 = {0.f,0.f,0.f,0.f};

    float4 ax, ay, bx, by;
    auto loadA = [&](int k0) {
        const float* src = A1; int kk = k0;
        if (SPLIT && k0 >= 768) { src = A2; kk = k0 - 768; }
        const float* ap = src + (size_t)(m0 + row) * lda + kk + kq;
        ax = *(const float4*)ap; ay = *(const float4*)(ap + 4);
    };
    auto loadB = [&](int k0) {
        const float* bp = B + (size_t)(k0 + 2 * kp) * ldb + n0 + nq;
        bx = *(const float4*)bp; by = *(const float4*)(bp + ldb);
    };
    loadA(0); loadB(0);

    for (int k0 = 0; k0 < K; k0 += 32) {
        __syncthreads();
        uint4 apk;
        apk.x = pack_trunc(ax.x, ax.y); apk.y = pack_trunc(ax.z, ax.w);
        apk.z = pack_trunc(ay.x, ay.y); apk.w = pack_trunc(ay.z, ay.w);
        *(uint4*)&As[row][kq] = apk;
        *(u32*)&Bs[nq + 0][2 * kp] = pack_trunc(bx.x, by.x);
        *(u32*)&Bs[nq + 1][2 * kp] = pack_trunc(bx.y, by.y);
        *(u32*)&Bs[nq + 2][2 * kp] = pack_trunc(bx.z, by.z);
        *(u32*)&Bs[nq + 3][2 * kp] = pack_trunc(bx.w, by.w);
        if (k0 + 32 < K) { loadA(k0 + 32); loadB(k0 + 32); }
        __syncthreads();
        bf16x8 af0 = *(const bf16x8*)&As[wr + l16][lk8];
        bf16x8 af1 = *(const bf16x8*)&As[wr + 16 + l16][lk8];
        bf16x8 bf0 = *(const bf16x8*)&Bs[wc + l16][lk8];
        bf16x8 bf1 = *(const bf16x8*)&Bs[wc + 16 + l16][lk8];
        acc00 = __builtin_amdgcn_mfma_f32_16x16x32_bf16(af0, bf0, acc00, 0, 0, 0);
        acc01 = __builtin_amdgcn_mfma_f32_16x16x32_bf16(af0, bf1, acc01, 0, 0, 0);
        acc10 = __builtin_amdgcn_mfma_f32_16x16x32_bf16(af1, bf0, acc10, 0, 0, 0);
        acc11 = __builtin_amdgcn_mfma_f32_16x16x32_bf16(af1, bf1, acc11, 0, 0, 0);
    }

#define EPI_FRAG(ACC, MF, NF)                                                  \
    {                                                                          \
        const int gcol = n0 + wc + (NF)*16 + l16;                              \
        const float bv = bias ? bias[gcol] : 0.f;                              \
        float v_[4];                                                           \
        _Pragma("unroll")                                                      \
        for (int r = 0; r < 4; r++) {                                          \
            float v = ACC[r] + bv;                                             \
            if (RELU) v = fmaxf(v, 0.f);                                       \
            v_[r] = v;                                                         \
        }                                                                      \
        const int lr0 = wr + (MF)*16 + r4;                                     \
        if (MODE == 3) {                                                       \
            const int lc = wc + (NF)*16 + l16;                                 \
            _Pragma("unroll")                                                  \
            for (int r = 0; r < 4; r++) Ts[lc][lr0 + r] = f16bits((f16)v_[r]); \
        } else {                                                               \
            _Pragma("unroll")                                                  \
            for (int r = 0; r < 4; r++) {                                      \
                const size_t off = (size_t)(m0 + lr0 + r) * ldc + gcol;        \
                if (MODE == 0) ((float*)C)[off] = v_[r];                       \
                else ((u16*)C)[off] = f16bits((f16)v_[r]);                     \
            }                                                                  \
        }                                                                      \
    }
    EPI_FRAG(acc00, 0, 0) EPI_FRAG(acc01, 0, 1)
    EPI_FRAG(acc10, 1, 0) EPI_FRAG(acc11, 1, 1)
#undef EPI_FRAG

    if (MODE == 3) {
        __syncthreads();
        u16* cb = (u16*)C + (size_t)(m0 >> 7) * (768 * 128) + (m0 & 127);
#pragma unroll
        for (int u = 0; u < 4; u++) {
            const int i = tid + u * 256;
            const int hl = i >> 4;
            const int s4 = (i & 15) << 2;
            ushort4 o;
            o.x = Ts[hl][s4 + 0]; o.y = Ts[hl][s4 + 1];
            o.z = Ts[hl][s4 + 2]; o.w = Ts[hl][s4 + 3];
            *(ushort4*)(cb + (size_t)(n0 + hl) * 128 + s4) = o;
        }
    }
}

// ---------------------------- phase bodies ---------------------------------
__device__ __forceinline__ void phase1(const Params& p, char* smem, int tid,
                                       unsigned bid, unsigned stride)
{
    for (unsigned job = bid; job < 768; job += stride) {
        const int z = job / 96, r = job % 96, my = r / 12, nx = r % 12;
        const int n = z & 3;
        if (z < 4)
            gemm_tile<2, false, false>(p.speech, nullptr, 768,
                p.W1 + (size_t)n * 1536 * 768, 768, p.b1 + n * 768,
                p.sxf + (size_t)n * 512 * 768, 768, 768, my * 64, nx * 64, smem, tid);
        else
            gemm_tile<3, false, false>(p.phon, nullptr, 768,
                p.W1 + (size_t)n * 1536 * 768 + 768 * 768, 768, nullptr,
                p.pyt + (size_t)n * 4 * 768 * 128, 0, 768, my * 64, nx * 64, smem, tid);
    }
}

__device__ __forceinline__ void phase2(const Params& p, char* smem, int tid,
                                       unsigned bid, unsigned stride)
{
    const int lane = tid & 63, w = tid >> 6;
    for (unsigned job = bid; job < 256; job += stride) {
        const int n = job >> 6, b = (job >> 4) & 3, t0 = (job & 15) * 8;
        f16x2 (*sxs)[768] = reinterpret_cast<f16x2(*)[768]>(smem);
        f16x2* w2s = reinterpret_cast<f16x2*>(smem + 24576);

        __syncthreads();
        for (int q = 0; q < 6; q++) {
            const int u = tid + q * 256;
            const int r = u / 192;
            const int h4 = (u % 192) * 4;
            ushort4 v = *(const ushort4*)(p.sxf + ((size_t)(n * 512 + b * 128 + t0 + r)) * 768 + h4);
            sxs[r][h4 + 0] = bcast2(splat2(v.x));
            sxs[r][h4 + 1] = bcast2(splat2(v.y));
            sxs[r][h4 + 2] = bcast2(splat2(v.z));
            sxs[r][h4 + 3] = bcast2(splat2(v.w));
        }
        for (int q = 0; q < 3; q++) {
            const int i = tid + q * 256;
            w2s[i] = bcast2(splat2(f16bits((f16)p.w2[n * 768 + i])));
        }
        __syncthreads();

        const f16x2* pypanel = (const f16x2*)(p.pyt + ((size_t)((n << 2) | b)) * 768 * 128) + lane;
        const f16x2 z2 = {(f16)0, (f16)0};

        float accA0 = 0.f, accA1 = 0.f, accB0 = 0.f, accB1 = 0.f;
        const int rA = 2 * w, rB = 2 * w + 1;

        f16x2 b0[16], b1[16];
#pragma unroll
        for (int j = 0; j < 16; j++) b0[j] = pypanel[(size_t)j * 64];
#pragma unroll
        for (int j = 0; j < 16; j++) b1[j] = pypanel[(size_t)(16 + j) * 64];

        auto compute = [&](const f16x2 (&buf)[16], int hbase) {
            f16x2 aA = z2, aB = z2;
#pragma unroll
            for (int j4 = 0; j4 < 16; j4 += 4) {
                uint4 sau = *(const uint4*)&sxs[rA][hbase + j4];
                uint4 sbu = *(const uint4*)&sxs[rB][hbase + j4];
                uint4 wvu = *(const uint4*)&w2s[hbase + j4];
                const u32 sa_[4] = {sau.x, sau.y, sau.z, sau.w};
                const u32 sb_[4] = {sbu.x, sbu.y, sbu.z, sbu.w};
                const u32 wv_[4] = {wvu.x, wvu.y, wvu.z, wvu.w};
#pragma unroll
                for (int j = 0; j < 4; j++) {
                    const f16x2 pv = buf[j4 + j];
                    const f16x2 wj = bcast2(wv_[j]);
                    f16x2 ra = __builtin_elementwise_max(bcast2(sa_[j]) + pv, z2);
                    f16x2 rb = __builtin_elementwise_max(bcast2(sb_[j]) + pv, z2);
                    aA = __builtin_elementwise_fma(ra, wj, aA);
                    aB = __builtin_elementwise_fma(rb, wj, aB);
                }
            }
            accA0 += (float)aA.x; accA1 += (float)aA.y;
            accB0 += (float)aB.x; accB1 += (float)aB.y;
        };

        for (int hc = 0; hc < 768; hc += 32) {
            compute(b0, hc);
            if (hc + 32 < 768) {
#pragma unroll
                for (int j = 0; j < 16; j++) b0[j] = pypanel[(size_t)(hc + 32 + j) * 64];
            }
            compute(b1, hc + 16);
            if (hc + 48 < 768) {
#pragma unroll
                for (int j = 0; j < 16; j++) b1[j] = pypanel[(size_t)(hc + 48 + j) * 64];
            }
        }

#pragma unroll
        for (int which = 0; which < 2; which++) {
            const float s0 = which ? accB0 : accA0;
            const float s1 = which ? accB1 : accA1;
            const int t = t0 + 2 * w + which;
            float mx = fmaxf(s0, s1);
#pragma unroll
            for (int off = 32; off; off >>= 1) mx = fmaxf(mx, __shfl_xor(mx, off, 64));
            const float e0 = expf(s0 - mx), e1 = expf(s1 - mx);
            float sm = e0 + e1;
#pragma unroll
            for (int off = 32; off; off >>= 1) sm += __shfl_xor(sm, off, 64);
            const float inv = 0.25f / sm;
            float2 pr; pr.x = e0 * inv; pr.y = e1 * inv;
            *(float2*)&p.probs[((size_t)(n * 512 + b * 128 + t)) * 128 + 2 * lane] = pr;
        }
    }
}

__device__ __forceinline__ void phase3(const Params& p, char* smem, int tid,
                                       unsigned bid, unsigned stride)
{
    for (unsigned job = bid; job < 512; job += stride) {
        const int m = job, b = m >> 7;
        float* attn = reinterpret_cast<float*>(smem);
        __syncthreads();
        if (tid < 128) {
            float a = 0.f;
#pragma unroll
            for (int n = 0; n < 4; n++)
                a += p.probs[((size_t)(n * 512) + m) * 128 + tid];
            attn[tid] = a;
        }
        __syncthreads();
        const float* ph = p.phon + (size_t)b * 128 * 768;
#pragma unroll
        for (int j = 0; j < 3; j++) {
            const int d = tid + 256 * j;
            float acc = 0.f;
#pragma unroll 8
            for (int s = 0; s < 128; s++)
                acc = fmaf(attn[s], ph[(size_t)s * 768 + d], acc);
            p.ctx[(size_t)m * 768 + d] = acc;
        }
    }
}

__device__ __forceinline__ void phase4(const Params& p, char* smem, int tid,
                                       unsigned bid, unsigned stride)
{
    for (unsigned job = bid; job < 192; job += stride) {
        const int my = job / 24, nx = job % 24;
        gemm_tile<0, true, true>(p.speech, p.ctx, 768, p.Wf1, 1536, p.bf1,
                                 p.hbuf, 1536, 1536, my * 64, nx * 64, smem, tid);
    }
}

__device__ __forceinline__ void phase5(const Params& p, char* smem, int tid,
                                       unsigned bid, unsigned stride)
{
    for (unsigned job = bid; job < 96; job += stride) {
        const int my = job / 12, nx = job % 12;
        gemm_tile<0, false, false>(p.hbuf, nullptr, 1536, p.Wf2, 768, p.bf2,
                                   p.outpre, 768, 1536, my * 64, nx * 64, smem, tid);
    }
}

__device__ __forceinline__ void phase6(const Params& p, char* smem, int tid,
                                       unsigned bid, unsigned stride)
{
    const int lane = tid & 63, w = tid >> 6;
    for (unsigned job = bid; job < 128; job += stride) {
        const int b = job >> 5, q = job & 31;
        const int rowg = b * 128 + q * 4 + w;
        float* Sred = reinterpret_cast<float*>(smem);
        __syncthreads();
        const float4* x4 = (const float4*)(p.outpre + (size_t)rowg * 768);
        float s = 0.f, ss = 0.f;
#pragma unroll
        for (int j = 0; j < 3; j++) {
            float4 v = x4[j * 64 + lane];
            s += v.x + v.y + v.z + v.w;
            ss += v.x * v.x + v.y * v.y + v.z * v.z + v.w * v.w;
        }
#pragma unroll
        for (int off = 32; off; off >>= 1) {
            s += __shfl_xor(s, off, 64);
            ss += __shfl_xor(ss, off, 64);
        }
        if (lane == 0) {
            const float mu = s * (1.f / 768.f);
            const float var = ss * (1.f / 768.f) - mu * mu;
            const float r = rsqrtf(var + LN_EPS_);
            p.rs[rowg] = r;
            Sred[w] = mu * r;
        }
        __syncthreads();
        if (tid == 0) p.prS[job] = Sred[0] + Sred[1] + Sred[2] + Sred[3];
    }
}

__device__ __forceinline__ void phase7(const Params& p, char* smem, int tid,
                                       unsigned bid, unsigned stride)
{
    for (unsigned job = bid; job < 12; job += stride) {
        const int b = job / 3, c = job % 3, d = c * 256 + tid;
        float* rsl = reinterpret_cast<float*>(smem);
        float* prl = rsl + 128;
        __syncthreads();
        if (tid < 128) rsl[tid] = p.rs[b * 128 + tid];
        else if (tid < 160) prl[tid - 128] = p.prS[b * 32 + (tid - 128)];
        __syncthreads();
        float S = 0.f;
#pragma unroll
        for (int i = 0; i < 32; i++) S += prl[i];
        float acc = 0.f;
#pragma unroll 8
        for (int t = 0; t < 128; t++)
            acc = fmaf(p.outpre[(size_t)(b * 128 + t) * 768 + d], rsl[t], acc);
        p.out[b * 768 + d] = p.g[d] * (acc - S) * (1.f / 128.f) + p.lb[d];
    }
}

// ---------------------------- kernels --------------------------------------
__global__ __launch_bounds__(256, 2) void mega_kernel(Params p)
{
    __shared__ __align__(16) char smem[SMEM_BYTES];
    const int tid = threadIdx.x;
    cg::grid_group grid = cg::this_grid();
    const unsigned bid = blockIdx.x, stride = gridDim.x;

    phase1(p, smem, tid, bid, stride); grid.sync();
    phase2(p, smem, tid, bid, stride); grid.sync();
    phase3(p, smem, tid, bid, stride); grid.sync();
    phase4(p, smem, tid, bid, stride); grid.sync();
    phase5(p, smem, tid, bid, stride); grid.sync();
    phase6(p, smem, tid, bid, stride); grid.sync();
    phase7(p, smem, tid, bid, stride);
}

template<int PH>
__global__ __launch_bounds__(256) void phase_kernel(Params p)
{
    __shared__ __align__(16) char smem[SMEM_BYTES];
    const int tid = threadIdx.x;
    const unsigned bid = blockIdx.x, stride = gridDim.x;
    if      (PH == 1) phase1(p, smem, tid, bid, stride);
    else if (PH == 2) phase2(p, smem, tid, bid, stride);
    else if (PH == 3) phase3(p, smem, tid, bid, stride);
    else if (PH == 4) phase4(p, smem, tid, bid, stride);
    else if (PH == 5) phase5(p, smem, tid, bid, stride);
    else if (PH == 6) phase6(p, smem, tid, bid, stride);
    else              phase7(p, smem, tid, bid, stride);
}

extern "C" void kernel_launch(void* const* d_in, const int* in_sizes, int n_in,
                              void* d_out, int out_size, void* d_ws, size_t ws_size,
                              hipStream_t stream)
{
    Params p;
    p.speech = (const float*)d_in[0];
    p.phon   = (const float*)d_in[1];
    p.W1     = (const float*)d_in[2];
    p.b1     = (const float*)d_in[3];
    p.w2     = (const float*)d_in[4];
    // d_in[5] = b2: softmax-invariant, unused
    p.Wf1    = (const float*)d_in[6];
    p.bf1    = (const float*)d_in[7];
    p.Wf2    = (const float*)d_in[8];
    p.bf2    = (const float*)d_in[9];
    p.g      = (const float*)d_in[10];
    p.lb     = (const float*)d_in[11];
    p.out    = (float*)d_out;

    char* w = (char*)d_ws;
    auto alloc = [&](size_t bytes) { char* q = w; w += (bytes + 1023) & ~(size_t)1023; return q; };
    p.sxf    = (u16*)alloc((size_t)NH_ * M_ * 768 * 2);
    p.pyt    = (u16*)alloc((size_t)NH_ * B_ * 768 * 128 * 2);
    p.probs  = (float*)alloc((size_t)NH_ * M_ * 128 * 4);
    p.ctx    = (float*)alloc((size_t)M_ * 768 * 4);
    p.hbuf   = (float*)alloc((size_t)M_ * 1536 * 4);
    p.outpre = (float*)alloc((size_t)M_ * 768 * 4);
    p.rs     = (float*)alloc(M_ * 4);
    p.prS    = (float*)alloc(128 * 4);

    // Size the cooperative grid from the runtime's own occupancy calculation
    // (grid <= occ * numCUs is the hard requirement for cooperative launch).
    int occ = 0;
    hipError_t qerr = hipOccupancyMaxActiveBlocksPerMultiprocessor(&occ, mega_kernel, 256, 0);
    hipError_t lerr = hipErrorUnknown;
    if (qerr == hipSuccess && occ >= 1) {
        const unsigned gb = (occ >= 2 ? 2u : 1u) * 256u;
        void* kargs[] = { (void*)&p };
        lerr = hipLaunchCooperativeKernel(reinterpret_cast<void*>(mega_kernel),
                                          dim3(gb), dim3(256), kargs, 0, stream);
    }
    if (lerr != hipSuccess) {
        // Fallback: same phase bodies as 7 ordinary launches.
        hipLaunchKernelGGL(phase_kernel<1>, dim3(768), dim3(256), 0, stream, p);
        hipLaunchKernelGGL(phase_kernel<2>, dim3(256), dim3(256), 0, stream, p);
        hipLaunchKernelGGL(phase_kernel<3>, dim3(512), dim3(256), 0, stream, p);
        hipLaunchKernelGGL(phase_kernel<4>, dim3(192), dim3(256), 0, stream, p);
        hipLaunchKernelGGL(phase_kernel<5>, dim3(96),  dim3(256), 0, stream, p);
        hipLaunchKernelGGL(phase_kernel<6>, dim3(128), dim3(256), 0, stream, p);
        hipLaunchKernelGGL(phase_kernel<7>, dim3(12),  dim3(256), 0, stream, p);
    }
}